// Round 10
// baseline (4233.271 us; speedup 1.0000x reference)
//
#include <hip/hip_runtime.h>
#include <stdint.h>

// ---------------------------------------------------------------------------
// LSTM decoder: B=256, S=1024, H=256, 4H=1024 gates (i,f,g,o).
// Round-10: EXACT-FIT register-file residency at 1 wave/EU.
// File geometry (established r2-r9): 512 regs/lane/SIMD; per wave budget =
// 512 / waves_per_eu, arch capped at 256, remainder accum (AGPR).
// 16 LSTM blocks x 4 waves (256 thr). Wave owns 16 nt x 8 kt = 128 W-frags:
//   64 frags (kt4-7)          -> AGPR quads (256 accum, asm("":"+a") pin,
//                                builtin MFMA consumes AGPR B directly)
//   28 frags (kt3 + kt2 hi12) -> arch VGPRs (112 regs)
//   36 frags (kt0,1 + kt2 lo4)-> LDS (144KB) + 16KB h-dbuf = 160KB exactly
// ZERO streamed W, target ZERO scratch (arch live ~238 <= 256).
// All MFMAs are builtins (hazard guards compiler-inserted; r6/r7-proven).
// ---------------------------------------------------------------------------

using bf16x8 = __attribute__((ext_vector_type(8))) __bf16;
using f32x4  = __attribute__((ext_vector_type(4))) float;
using u32x4  = __attribute__((ext_vector_type(4))) uint32_t;
using u32x2  = __attribute__((ext_vector_type(2))) uint32_t;
using u16x2  = __attribute__((ext_vector_type(2))) uint16_t;

#define NCHUNK 8

// workspace layout (bytes)
#define XS_OFF   0ull
#define XS_SZ    134217728ull
#define WIH_OFF  (XS_OFF + XS_SZ)
#define W_SZ     524288ull
#define WHH_OFF  (WIH_OFF + W_SZ)
#define XP0_OFF  (WHH_OFF + W_SZ)
#define XP_SZ    67108864ull          // 16 blk * 128 s * 4 w * 2 half * 64 lane * 64B
#define XP1_OFF  (XP0_OFF + XP_SZ)
#define HST_OFF  (XP1_OFF + XP_SZ)    // 16 blk * 8KB
#define HST_SZ   131072ull
#define CST_OFF  (HST_OFF + HST_SZ)   // 16 blk * 4 w * 64 l * 16 fp32
#define CST_SZ   262144ull
#define BIAS_OFF (CST_OFF + CST_SZ)

// LSTM LDS: 4 waves * 36 frags * 1KB = 147456, then 2 * 8KB h double-buffer
#define WLDS_PER_WAVE 36864
#define HOFF   147456
#define LDS_BYTES 163840

#define SC_IFO -1.442695041f     // -log2(e)
#define SC_G   -2.885390082f     // -2*log2(e)

__device__ __forceinline__ uint16_t f2bf(float f) {
  uint32_t x = __float_as_uint(f);
  x += 0x7fffu + ((x >> 16) & 1u);
  return (uint16_t)(x >> 16);
}
__device__ __forceinline__ float bf2f(uint16_t u) {
  return __uint_as_float(((uint32_t)u) << 16);
}
__device__ __forceinline__ float frcp(float x) { return __builtin_amdgcn_rcpf(x); }
__device__ __forceinline__ float exp2a(float x) {
  float r; asm("v_exp_f32 %0, %1" : "=v"(r) : "v"(x)); return r;
}
__device__ __forceinline__ f32x4 mfma16(u32x4 a, u32x4 b, f32x4 c) {
  return __builtin_amdgcn_mfma_f32_16x16x32_bf16(
      __builtin_bit_cast(bf16x8, a), __builtin_bit_cast(bf16x8, b), c, 0, 0, 0);
}

// ---------------------------------------------------------------------------
// P1: pack shifted input sequence (S-MAJOR rows: r = s*256 + b) into
// A-fragment layout xsp[m16][kt][lane][8bf16].  (verified)
// ---------------------------------------------------------------------------
__global__ __launch_bounds__(256) void pack_x_k(const float* __restrict__ x,
                                                const float* __restrict__ hn,
                                                uint16_t* __restrict__ xsp) {
  __shared__ uint16_t tile[64 * 256];
  const int t = blockIdx.x;
  const int tid = threadIdx.x;
  for (int pass = 0; pass < 2; ++pass) {
    const int r = tid >> 2;
    const int qq = tid & 3;
    const int rg = t * 128 + pass * 64 + r;
    const int s = rg >> 8, b = rg & 255;
    const float* src = s ? (x + ((size_t)b * 1024 + (s - 1)) * 256)
                         : (hn + (size_t)b * 256);
#pragma unroll
    for (int i = 0; i < 64; i += 2) {
      float2 v = *(const float2*)(src + qq * 64 + i);
      uint32_t kb = (uint32_t)(qq * 64 + i) * 2u;
      uint32_t addr = (uint32_t)r * 512u + (kb ^ (((uint32_t)r & 7u) << 4));
      u16x2 pr; pr.x = f2bf(v.x); pr.y = f2bf(v.y);
      *(u16x2*)((char*)tile + addr) = pr;
    }
    __syncthreads();
#pragma unroll
    for (int ff = 0; ff < 8; ++ff) {
      int task = ff * 256 + tid;
      int frag = task >> 6, lam = task & 63;
      int mt = frag >> 3, kt = frag & 7;
      int row = mt * 16 + (lam & 15);
      uint32_t kb = (uint32_t)(kt * 64 + (lam >> 4) * 16);
      u32x4 d = *(const u32x4*)((const char*)tile + row * 512 +
                                (kb ^ (((uint32_t)row & 7u) << 4)));
      size_t m16 = (size_t)t * 8 + pass * 4 + mt;
      *(u32x4*)(xsp + ((m16 * 8 + kt) * 64 + lam) * 8) = d;
    }
    __syncthreads();
  }
}

// ---------------------------------------------------------------------------
// P2: W packs (pre-scaled by -log2e / -2log2e), bias, h0 A-frag state,
// c0 per-lane state ([blk][w][l][16] layout).  (verified r9)
// ---------------------------------------------------------------------------
__global__ __launch_bounds__(256) void pack_misc_k(
    const float* __restrict__ wih, const float* __restrict__ whh,
    const float* __restrict__ bih, const float* __restrict__ bhh,
    const float* __restrict__ hn, const float* __restrict__ cn,
    uint16_t* __restrict__ wihp, uint16_t* __restrict__ whhp,
    float* __restrict__ bias, uint16_t* __restrict__ hst, float* __restrict__ cst) {
  const int blk = blockIdx.x, tid = threadIdx.x;
  if (blk < 32) {
    __shared__ uint16_t tile[64 * 256];
    const float* W = (blk < 16) ? wih : whh;
    uint16_t* WP = (blk < 16) ? wihp : whhp;
    const int rowbase = (blk & 15) * 64;
    const int r = tid >> 2, qq = tid & 3;
    const int n = rowbase + r;
    const float sc = ((n >> 8) == 2) ? SC_G : SC_IFO;
    const float* src = W + (size_t)n * 256;
#pragma unroll
    for (int i = 0; i < 64; i += 2) {
      float2 v = *(const float2*)(src + qq * 64 + i);
      uint32_t kb = (uint32_t)(qq * 64 + i) * 2u;
      uint32_t addr = (uint32_t)r * 512u + (kb ^ (((uint32_t)r & 7u) << 4));
      u16x2 pr; pr.x = f2bf(v.x * sc); pr.y = f2bf(v.y * sc);
      *(u16x2*)((char*)tile + addr) = pr;
    }
    __syncthreads();
#pragma unroll
    for (int ff = 0; ff < 8; ++ff) {
      int task = ff * 256 + tid;
      int frag = task >> 6, lam = task & 63;
      int mt = frag >> 3, kt = frag & 7;
      int row = mt * 16 + (lam & 15);
      uint32_t kb = (uint32_t)(kt * 64 + (lam >> 4) * 16);
      u32x4 d = *(const u32x4*)((const char*)tile + row * 512 +
                                (kb ^ (((uint32_t)row & 7u) << 4)));
      size_t nt = (size_t)(blk & 15) * 4 + mt;
      *(u32x4*)(WP + ((nt * 8 + kt) * 64 + lam) * 8) = d;
    }
  } else if (blk == 32) {
    for (int i = tid; i < 4096; i += 256) {
      float sc = ((i >> 8) == 2) ? SC_G : SC_IFO;
      bias[i] = (bih[i] + bhh[i]) * sc;
    }
  } else if (blk == 33) {
    // h_state[lblk][kt][lam][8] (A-frag layout)
    for (int it = 0; it < 32; ++it) {
      int task = it * 256 + tid;
      int lam = task & 63;
      int kt = (task >> 6) & 7;
      int lb = task >> 9;
      int b = lb * 16 + (lam & 15);
      int k0 = kt * 32 + (lam >> 4) * 8;
      union { uint16_t s[8]; u32x4 v; } u;
#pragma unroll
      for (int j = 0; j < 8; ++j) u.s[j] = f2bf(hn[(size_t)b * 256 + k0 + j]);
      *(u32x4*)(hst + (size_t)task * 8) = u.v;
    }
  } else {
    // blk 34,35: cst[blk][w][l][16], v = half*8 + jt*4 + q
    for (int it = 0; it < 128; ++it) {
      int idx = (blk - 34) * 32768 + it * 256 + tid;
      int v = idx & 15;
      int lq = (idx >> 4) & 63;
      int ww = (idx >> 10) & 3;
      int lb = idx >> 12;
      int h = v >> 3, jt = (v >> 2) & 1, q = v & 3;
      int b = lb * 16 + (lq >> 4) * 4 + q;
      int j = (ww * 4 + h * 2 + jt) * 16 + (lq & 15);
      cst[idx] = cn[(size_t)b * 256 + j];
    }
  }
}

// ---------------------------------------------------------------------------
// fused: blocks 0-15 persistent LSTM chunk `lstm_chunk` (128 steps);
//        blocks 16..271 x_proj GEMM chunk `gemm_chunk`.
// ---------------------------------------------------------------------------
__global__
__attribute__((amdgpu_flat_work_group_size(256, 256)))
__attribute__((amdgpu_waves_per_eu(1, 1)))
void fused_k(
    const uint16_t* __restrict__ xsp, const uint16_t* __restrict__ wihp,
    const uint16_t* __restrict__ whhp, const float* __restrict__ bias,
    uint16_t* __restrict__ xp0, uint16_t* __restrict__ xp1,
    uint16_t* __restrict__ hst, float* __restrict__ cst,
    float* __restrict__ out, int lstm_chunk, int gemm_chunk) {
  extern __shared__ __align__(16) char lds[];
  const int tid = threadIdx.x;
  const int l = tid & 63;
  const int w = tid >> 6;

  if (blockIdx.x < 16) {
    // ======================= LSTM path =======================
    if (lstm_chunk < 0) return;
    const int c = lstm_chunk;
    const int blk = blockIdx.x;
    const uint16_t* __restrict__ xp = (c & 1) ? xp1 : xp0;
    char* wl = lds + w * WLDS_PER_WAVE;

    // ---- W residency: 64 frags AGPR, 28 frags VGPR, 36 frags LDS ----
    u32x4 wv[28];    // kt2 fi4-15 -> [fi-4]; kt3 all fi -> [12+fi]
    u32x4 wa[64];    // kt4-7 all fi -> [(kt-4)*16+fi], pinned to AGPR quads
#pragma unroll
    for (int fi = 0; fi < 16; ++fi) {
      int nt = (fi & 3) * 16 + w * 4 + (fi >> 2);
#pragma unroll
      for (int kt = 0; kt < 8; ++kt) {
        u32x4 d = *(const u32x4*)(whhp + (((size_t)nt * 8 + kt) * 64 + l) * 8);
        if (kt < 2) {
          *(u32x4*)(wl + (kt * 16 + fi) * 1024 + l * 16) = d;
        } else if (kt == 2 && fi < 4) {
          *(u32x4*)(wl + (32 + fi) * 1024 + l * 16) = d;
        } else if (kt == 2) {
          wv[fi - 4] = d;
        } else if (kt == 3) {
          wv[12 + fi] = d;
        } else {
          asm volatile("" : "+a"(d));   // pin as contiguous AGPR quad
          wa[(kt - 4) * 16 + fi] = d;
        }
      }
    }
    // c registers (16 cells/lane)
    float creg[16];
    {
      const float* cs = cst + ((size_t)(blk * 4 + w) * 64 + l) * 16;
#pragma unroll
      for (int v = 0; v < 16; ++v) creg[v] = cs[v];
    }
    // h(0) -> buffer 0
    {
      const char* src = (const char*)hst + (size_t)blk * 8192 + (size_t)tid * 32;
      *(u32x4*)(lds + HOFF + tid * 32) = *(const u32x4*)src;
      *(u32x4*)(lds + HOFF + tid * 32 + 16) = *(const u32x4*)(src + 16);
    }
    const char* xpb = (const char*)xp +
        ((((size_t)blk * 128) * 4 + w) * 2) * 4096 + (size_t)l * 64;
    float* ob = out + ((size_t)(blk * 16 + (l >> 4) * 4) * 1024 + (size_t)c * 128) * 256 + (l & 15);
    __syncthreads();

    union XV { uint16_t sv[32]; u32x4 v[4]; };

    int p = 0;
#pragma unroll 1
    for (int s = 0; s < 128; ++s) {
      const char* hb = lds + HOFF + p * 8192 + l * 16;
      char* hw = lds + HOFF + (p ^ 1) * 8192;
      const char* xc = xpb + (size_t)s * 32768;

      // h fragments once per step, shared by both halves
      u32x4 a[8];
#pragma unroll
      for (int kt = 0; kt < 8; ++kt) a[kt] = *(const u32x4*)(hb + kt * 1024);

      auto do_half = [&](int half, XV& xv) {
        f32x4 acc[2][4] = {};   // [jt][g]
#pragma unroll
        for (int kt = 0; kt < 8; ++kt) {
#pragma unroll
          for (int jt = 0; jt < 2; ++jt)
#pragma unroll
            for (int g = 0; g < 4; ++g) {
              int fi = (half * 2 + jt) * 4 + g;
              u32x4 b;
              if (kt < 2)
                b = *(const u32x4*)(wl + (kt * 16 + fi) * 1024 + l * 16);
              else if (kt == 2 && fi < 4)
                b = *(const u32x4*)(wl + (32 + fi) * 1024 + l * 16);
              else if (kt == 2)
                b = wv[fi - 4];
              else if (kt == 3)
                b = wv[12 + fi];
              else
                b = wa[(kt - 4) * 16 + fi];
              acc[jt][g] = mfma16(a[kt], b, acc[jt][g]);
            }
        }
#pragma unroll
        for (int jt = 0; jt < 2; ++jt) {
          const int j = (w * 4 + half * 2 + jt) * 16 + (l & 15);
          char* hwj = hw + (j >> 5) * 1024 + ((j >> 3) & 3) * 256 +
                      (l >> 4) * 64 + (j & 7) * 2;
          float* obh = ob + (size_t)s * 256 + (w * 4 + half * 2 + jt) * 16;
#pragma unroll
          for (int q = 0; q < 4; ++q) {
            float xi = acc[jt][0][q] + bf2f(xv.sv[0 * 8 + jt * 4 + q]);
            float xf = acc[jt][1][q] + bf2f(xv.sv[1 * 8 + jt * 4 + q]);
            float xg = acc[jt][2][q] + bf2f(xv.sv[2 * 8 + jt * 4 + q]);
            float xo = acc[jt][3][q] + bf2f(xv.sv[3 * 8 + jt * 4 + q]);
            float I = frcp(1.f + exp2a(xi));
            float F = frcp(1.f + exp2a(xf));
            float T = fmaf(2.f, frcp(1.f + exp2a(xg)), -1.f);
            float O = frcp(1.f + exp2a(xo));
            int ci = half * 8 + jt * 4 + q;
            float cv = fmaf(F, creg[ci], I * T);
            creg[ci] = cv;
            float hv = O * fmaf(2.f, frcp(1.f + exp2a(SC_G * cv)), -1.f);
            obh[(size_t)q * 262144] = hv;
            *(uint16_t*)(hwj + q * 16) = f2bf(hv);
          }
        }
      };

      XV xv0;
      xv0.v[0] = *(const u32x4*)(xc);
      xv0.v[1] = *(const u32x4*)(xc + 16);
      xv0.v[2] = *(const u32x4*)(xc + 32);
      xv0.v[3] = *(const u32x4*)(xc + 48);
      do_half(0, xv0);
      XV xv1;
      xv1.v[0] = *(const u32x4*)(xc + 4096);
      xv1.v[1] = *(const u32x4*)(xc + 4096 + 16);
      xv1.v[2] = *(const u32x4*)(xc + 4096 + 32);
      xv1.v[3] = *(const u32x4*)(xc + 4096 + 48);
      do_half(1, xv1);
      __syncthreads();
      p ^= 1;
    }
    // write back carry state
    {
      const char* src = lds + HOFF + p * 8192 + tid * 32;
      char* dst = (char*)hst + (size_t)blk * 8192 + (size_t)tid * 32;
      *(u32x4*)dst = *(const u32x4*)src;
      *(u32x4*)(dst + 16) = *(const u32x4*)(src + 16);
      float* cs = cst + ((size_t)(blk * 4 + w) * 64 + l) * 16;
#pragma unroll
      for (int v = 0; v < 16; ++v) cs[v] = creg[v];
    }
    return;
  }

  // ======================= x_proj GEMM path =======================
  if (gemm_chunk < 0) return;
  const int cg = gemm_chunk;
  const int bid = blockIdx.x - 16;   // 0..255
  const int bb = bid & 15;           // batch group
  const int st = bid >> 4;           // s-group of 8
  uint16_t* __restrict__ xpo = (cg & 1) ? xp1 : xp0;

  float badd[4][4];                  // [g][jj]
#pragma unroll
  for (int g = 0; g < 4; ++g)
#pragma unroll
    for (int jj = 0; jj < 4; ++jj)
      badd[g][jj] = bias[(g * 16 + w * 4 + jj) * 16 + (l & 15)];

#pragma unroll 1
  for (int pr = 0; pr < 4; ++pr) {
    f32x4 acc[2][16] = {};           // [t][g*4+jj]
#pragma unroll
    for (int kt = 0; kt < 8; ++kt) {
      u32x4 av[2];
#pragma unroll
      for (int t = 0; t < 2; ++t) {
        size_t m16 = (size_t)(cg * 128 + st * 8 + pr * 2 + t) * 16 + bb;
        av[t] = *(const u32x4*)(xsp + ((m16 * 8 + kt) * 64 + l) * 8);
      }
      u32x4 bv[16];
#pragma unroll
      for (int fi = 0; fi < 16; ++fi) {
        int g = fi >> 2, jj = fi & 3;
        size_t nt = (size_t)(g * 16 + w * 4 + jj);
        bv[fi] = *(const u32x4*)(wihp + ((nt * 8 + kt) * 64 + l) * 8);
      }
#pragma unroll
      for (int t = 0; t < 2; ++t)
#pragma unroll
        for (int fi = 0; fi < 16; ++fi)
          acc[t][fi] = mfma16(av[t], bv[fi], acc[t][fi]);
    }
#pragma unroll
    for (int t = 0; t < 2; ++t) {
      int s = st * 8 + pr * 2 + t;
#pragma unroll
      for (int jj = 0; jj < 4; ++jj) {
        int half = jj >> 1, jt = jj & 1;
        char* dst = (char*)xpo +
            ((((size_t)bb * 128 + s) * 4 + w) * 2 + half) * 4096 +
            (size_t)l * 64 + jt * 8;
#pragma unroll
        for (int g = 0; g < 4; ++g) {
          union { uint16_t sv[4]; u32x2 v2; } pk;
#pragma unroll
          for (int q = 0; q < 4; ++q)
            pk.sv[q] = f2bf(acc[t][g * 4 + jj][q] + badd[g][jj]);
          *(u32x2*)(dst + g * 16) = pk.v2;
        }
      }
    }
  }
}

// ---------------------------------------------------------------------------
extern "C" void kernel_launch(void* const* d_in, const int* in_sizes, int n_in,
                              void* d_out, int out_size, void* d_ws, size_t ws_size,
                              hipStream_t stream) {
  const float* x   = (const float*)d_in[0];
  const float* hn  = (const float*)d_in[1];
  const float* cn  = (const float*)d_in[2];
  const float* wih = (const float*)d_in[3];
  const float* whh = (const float*)d_in[4];
  const float* bih = (const float*)d_in[5];
  const float* bhh = (const float*)d_in[6];
  float* out = (float*)d_out;
  char* ws = (char*)d_ws;

  uint16_t* xsp  = (uint16_t*)(ws + XS_OFF);
  uint16_t* wihp = (uint16_t*)(ws + WIH_OFF);
  uint16_t* whhp = (uint16_t*)(ws + WHH_OFF);
  uint16_t* xp0  = (uint16_t*)(ws + XP0_OFF);
  uint16_t* xp1  = (uint16_t*)(ws + XP1_OFF);
  uint16_t* hst  = (uint16_t*)(ws + HST_OFF);
  float*    cst  = (float*)(ws + CST_OFF);
  float*    bias = (float*)(ws + BIAS_OFF);

  hipFuncSetAttribute(reinterpret_cast<const void*>(fused_k),
                      hipFuncAttributeMaxDynamicSharedMemorySize, LDS_BYTES);

  hipLaunchKernelGGL(pack_x_k, dim3(2048), dim3(256), 0, stream, x, hn, xsp);
  hipLaunchKernelGGL(pack_misc_k, dim3(36), dim3(256), 0, stream,
                     wih, whh, bih, bhh, hn, cn, wihp, whhp, bias, hst, cst);
  for (int c = 0; c <= NCHUNK; ++c) {
    int lc = c - 1;
    int gc = (c < NCHUNK) ? c : -1;
    hipLaunchKernelGGL(fused_k, dim3(272), dim3(256), LDS_BYTES, stream,
                       xsp, wihp, whhp, bias, xp0, xp1, hst, cst, out, lc, gc);
  }
}